// Round 5
// baseline (407.674 us; speedup 1.0000x reference)
//
#include <hip/hip_runtime.h>
#include <hip/hip_bf16.h>

// BinaryTreeLSTM  B=64, L=1024, IN_DIM=300, MEM=256 — bf16 MFMA v5.
//
// Deep-pipelined GEMM (T3+T4+T5 port of the 256^2 8-phase template):
//  - block 256 rows x NO o-cols x NG gates (eff 256x256), 512 threads = 8 waves
//    (4 wm x 2 wn), wave tile 64r x NO/2 x NG -> per K-32 half: 32 MFMA,
//    12 ds_read_b128, 4 global_load_lds(16B).
//  - LDS: 3 rotating half-buffers x (A 16KB + B 16KB) = 96KB. While computing
//    half h, half h+1 is staged-complete and half h+2 is being issued.
//  - counted s_waitcnt vmcnt(4) at each half boundary (never 0 in steady
//    state), raw s_barrier, sched_barrier(0) fence after, setprio(1) around
//    MFMA clusters. K-loop fully unrolled -> static buffer indices.
//  - both-sides swizzle identical to v4 (verified 0 bank conflicts):
//    A slot = (q + ((row>>1)&3))&3, B slot = q ^ ((o>>1)&3) baked into pack.
//  - gates de-interleaved (col j = g*256+o) -> gate combine lane-local.
//  - c carried fp32, h carried bf16.

typedef __attribute__((ext_vector_type(8))) short bf16x8;
typedef __attribute__((ext_vector_type(4))) float f32x4;

__device__ __forceinline__ float fsig(float x)  { return 1.f / (1.f + __expf(-x)); }
__device__ __forceinline__ float ftanh(float x) { return 1.f - 2.f / (__expf(2.f * x) + 1.f); }
__device__ __forceinline__ ushort f2bf(float x) {
    __hip_bfloat16 b = __float2bfloat16(x);
    return *reinterpret_cast<ushort*>(&b);
}

__device__ __forceinline__ void gld_lds16(const void* g, void* l) {
    __builtin_amdgcn_global_load_lds((const __attribute__((address_space(1))) void*)g,
                                     (__attribute__((address_space(3))) void*)l, 16, 0, 0);
}

// ---------------- embs fp32 -> bf16 (pad K 300->320) ----------------
__global__ void conv_embs(const float* __restrict__ E, ushort* __restrict__ Eb)
{
    int tid = blockIdx.x * 256 + threadIdx.x;
    int row = tid / 80;
    int k = (tid - row * 80) * 4;
    float4 v = make_float4(0.f, 0.f, 0.f, 0.f);
    if (k < 300) v = *(const float4*)(E + (size_t)row * 300 + k);
    ushort4 o;
    o.x = f2bf(v.x); o.y = f2bf(v.y); o.z = f2bf(v.z); o.w = f2bf(v.w);
    *(ushort4*)(Eb + (size_t)row * 320 + k) = o;
}

// ---------------- weight pack kernels (identical swizzle to v4) ----------------
// chunk (t, g, o, slot) holds B[k = t*32 + q*8 + e][g*256+o], q = slot ^ ((o>>1)&3)
__global__ void pack_leaf_k(const float* __restrict__ Wcx, const float* __restrict__ Wox,
                            const float* __restrict__ bcx, const float* __restrict__ box,
                            ushort* __restrict__ Wb, float* __restrict__ bp)
{
    int idx = blockIdx.x * 256 + threadIdx.x;
    if (idx < 163840) {
        int e = idx & 7, slot = (idx >> 3) & 3, o = (idx >> 5) & 255;
        int g = (idx >> 13) & 1, t = idx >> 14;
        int q = slot ^ ((o >> 1) & 3);
        int k = t * 32 + q * 8 + e;
        float v = 0.f;
        if (k < 300) v = g ? Wox[o * 300 + k] : Wcx[o * 300 + k];
        Wb[idx] = f2bf(v);
    }
    if (idx < 512) {
        int g = idx >> 8, o = idx & 255;
        bp[idx] = g ? box[o] : bcx[o];
    }
}

__global__ void pack_level_k(const float* __restrict__ Wl, const float* __restrict__ Wr,
                             const float* __restrict__ bl, const float* __restrict__ br,
                             ushort* __restrict__ Wb, float* __restrict__ bp)
{
    int idx = blockIdx.x * 256 + threadIdx.x;
    if (idx < 524288) {
        int e = idx & 7, slot = (idx >> 3) & 3, o = (idx >> 5) & 255;
        int g = (idx >> 13) & 3, t = idx >> 15;
        int q = slot ^ ((o >> 1) & 3);
        int k = t * 32 + q * 8 + e;
        float v = (k < 256) ? Wl[(g * 256 + o) * 256 + k]
                            : Wr[(g * 256 + o) * 256 + (k - 256)];
        Wb[idx] = f2bf(v);
    }
    if (idx < 1024) bp[idx] = bl[idx] + br[idx];
}

// ---------------- fused deep-pipelined MFMA GEMM ----------------
// NG=2 leaf (NN=4, NO=128), NG=4 level (NN=2, NO=64).
// MODE 0 = leaf, 1 = level (h->bf16), 2 = last level (h->fp32)

template<int NG, int HALVES, int MODE>
__global__ __launch_bounds__(512, 2)
void mfma_gemm(const ushort* __restrict__ A,     // (M, HALVES*32) bf16 row-major
               const ushort* __restrict__ Wb,    // packed weights
               const float* __restrict__ bp,     // (NG*256)
               const float* __restrict__ Cprev,  // (M, 512) fp32, levels only
               float* __restrict__ c_out,        // (M, 256) fp32
               ushort* __restrict__ h_out,       // (M, 256) bf16 (MODE 0/1)
               float* __restrict__ hf_out,       // (M, 256) fp32 (MODE 2)
               int M)
{
    constexpr int NN = 8 / NG;            // n-frags per wave
    constexpr int K = HALVES * 32;
    constexpr int NO = NN * 32;           // o-cols per block
    constexpr int GCH = NO * 4;           // local B chunks per gate
    constexpr size_t BSTR = (size_t)NG * 1024 * 8;  // Wb ushorts per half

    // 3 rotating half-buffers: [buf][A chunks 0..1023 | B chunks 1024..2047]
    __shared__ __align__(16) ushort Buf[3][2048 * 8];

    const int tid = threadIdx.x;
    const int wid = tid >> 6, ln = tid & 63;
    const int lq = ln >> 4, lr = ln & 15;
    const int wm = wid >> 1, wn = wid & 1;
    const int rowBlk = blockIdx.x * 256;
    const int o0 = blockIdx.y * NO;

    f32x4 acc[4][NN][NG];
#pragma unroll
    for (int m = 0; m < 4; ++m)
#pragma unroll
        for (int n = 0; n < NN; ++n)
#pragma unroll
            for (int g = 0; g < NG; ++g) acc[m][n][g] = f32x4{0.f, 0.f, 0.f, 0.f};

    // ---- staging sources (4 glds per thread per half: A0 A1 B0 B1)
    const int rc0 = tid >> 2,        sl = tid & 3;
    const int rc1 = rc0 + 128;
    const int q0 = (sl - ((rc0 >> 1) & 3)) & 3;
    const int q1 = (sl - ((rc1 >> 1) & 3)) & 3;
    const ushort* aS0 = A + (size_t)min(rowBlk + rc0, M - 1) * K + q0 * 8;
    const ushort* aS1 = A + (size_t)min(rowBlk + rc1, M - 1) * K + q1 * 8;
    const int g0 = tid / GCH,         w0 = tid % GCH;
    const int g1 = (512 + tid) / GCH, w1 = (512 + tid) % GCH;
    const ushort* bS0 = Wb + ((size_t)g0 * 1024 + o0 * 4 + w0) * 8;
    const ushort* bS1 = Wb + ((size_t)g1 * 1024 + o0 * 4 + w1) * 8;

    // ---- read offsets (ushort units), all compile-time after unroll
    int aOff[4];
#pragma unroll
    for (int m = 0; m < 4; ++m) {
        int row = wm * 64 + m * 16 + lr;
        aOff[m] = (row * 4 + ((lq + ((row >> 1) & 3)) & 3)) * 8;
    }
    int bOff[NN][NG];
#pragma unroll
    for (int n = 0; n < NN; ++n) {
        int ol = wn * (NO / 2) + n * 16 + lr;
#pragma unroll
        for (int g = 0; g < NG; ++g)
            bOff[n][g] = (1024 + g * GCH + ol * 4 + (lq ^ ((ol >> 1) & 3))) * 8;
    }

    // ---- prologue: stage halves 0,1 ; wait for half 0 (4 newest may fly)
    {
        ushort* d0 = &Buf[0][0];
        gld_lds16(aS0, d0 + tid * 8);
        gld_lds16(aS1, d0 + (512 + tid) * 8);
        gld_lds16(bS0, d0 + (1024 + tid) * 8);
        gld_lds16(bS1, d0 + (1536 + tid) * 8);
        ushort* d1 = &Buf[1][0];
        gld_lds16(aS0 + 32, d1 + tid * 8);
        gld_lds16(aS1 + 32, d1 + (512 + tid) * 8);
        gld_lds16(bS0 + BSTR, d1 + (1024 + tid) * 8);
        gld_lds16(bS1 + BSTR, d1 + (1536 + tid) * 8);
    }
    asm volatile("s_waitcnt vmcnt(4)" ::: "memory");
    __builtin_amdgcn_s_barrier();
    __builtin_amdgcn_sched_barrier(0);

#pragma unroll
    for (int h = 0; h < HALVES; ++h) {
        const ushort* bb = &Buf[h % 3][0];
        ushort* dn = &Buf[(h + 2) % 3][0];
        const bool st = (h + 2 < HALVES);

        bf16x8 a[4];
#pragma unroll
        for (int m = 0; m < 4; ++m)
            a[m] = *(const bf16x8*)(bb + aOff[m]);

        // phase 0: issue next A staging, MFMA cluster 0 (flat frags 0..3)
        if (st) {
            gld_lds16(aS0 + (size_t)(h + 2) * 32, dn + tid * 8);
            gld_lds16(aS1 + (size_t)(h + 2) * 32, dn + (512 + tid) * 8);
        }
        __builtin_amdgcn_s_setprio(1);
#pragma unroll
        for (int f = 0; f < 4; ++f) {
            const int n = f / NG, g = f % NG;
            bf16x8 b = *(const bf16x8*)(bb + bOff[n][g]);
#pragma unroll
            for (int m = 0; m < 4; ++m)
                acc[m][n][g] = __builtin_amdgcn_mfma_f32_16x16x32_bf16(a[m], b, acc[m][n][g], 0, 0, 0);
        }
        __builtin_amdgcn_s_setprio(0);

        // phase 1: issue next B staging, MFMA cluster 1 (flat frags 4..7)
        if (st) {
            gld_lds16(bS0 + (size_t)(h + 2) * BSTR, dn + (1024 + tid) * 8);
            gld_lds16(bS1 + (size_t)(h + 2) * BSTR, dn + (1536 + tid) * 8);
        }
        __builtin_amdgcn_s_setprio(1);
#pragma unroll
        for (int f = 4; f < 8; ++f) {
            const int n = f / NG, g = f % NG;
            bf16x8 b = *(const bf16x8*)(bb + bOff[n][g]);
#pragma unroll
            for (int m = 0; m < 4; ++m)
                acc[m][n][g] = __builtin_amdgcn_mfma_f32_16x16x32_bf16(a[m], b, acc[m][n][g], 0, 0, 0);
        }
        __builtin_amdgcn_s_setprio(0);

        // half boundary: counted drain (never 0 while staging), barrier, fence
        if (h + 1 < HALVES) {
            if (st) asm volatile("s_waitcnt vmcnt(4)" ::: "memory");
            else    asm volatile("s_waitcnt vmcnt(0)" ::: "memory");
            __builtin_amdgcn_s_barrier();
            __builtin_amdgcn_sched_barrier(0);
        }
    }

    // ---- epilogue: D col = lr (within 16), row = 4*lq + j
#pragma unroll
    for (int m = 0; m < 4; ++m) {
        const int row0 = rowBlk + wm * 64 + m * 16 + lq * 4;
#pragma unroll
        for (int n = 0; n < NN; ++n) {
            const int col = o0 + wn * (NO / 2) + n * 16 + lr;
            if constexpr (MODE == 0) {
                const float bc = bp[col], bo = bp[256 + col];
#pragma unroll
                for (int j = 0; j < 4; ++j) {
                    int row = row0 + j;
                    if (row < M) {
                        float cv = acc[m][n][0][j] + bc;
                        float ov = acc[m][n][1][j] + bo;
                        c_out[(size_t)row * 256 + col] = cv;
                        h_out[(size_t)row * 256 + col] = f2bf(fsig(ov) * ftanh(cv));
                    }
                }
            } else {
                const float bi  = bp[col],       blf = bp[256 + col];
                const float brf = bp[512 + col], bu  = bp[768 + col];
#pragma unroll
                for (int j = 0; j < 4; ++j) {
                    int row = row0 + j;
                    if (row < M) {
                        float gi = fsig(acc[m][n][0][j] + bi);
                        float lf = fsig(acc[m][n][1][j] + blf);
                        float rf = fsig(acc[m][n][2][j] + brf);
                        float gu = ftanh(acc[m][n][3][j] + bu);
                        float lc = Cprev[(size_t)row * 512 + col];
                        float rc = Cprev[(size_t)row * 512 + 256 + col];
                        float cv = gi * gu + lf * lc + rf * rc;
                        float hv = ftanh(cv);
                        c_out[(size_t)row * 256 + col] = cv;
                        if constexpr (MODE == 2) hf_out[(size_t)row * 256 + col] = hv;
                        else                     h_out[(size_t)row * 256 + col] = f2bf(hv);
                    }
                }
            }
        }
    }
}

// ---------------- host ----------------

extern "C" void kernel_launch(void* const* d_in, const int* in_sizes, int n_in,
                              void* d_out, int out_size, void* d_ws, size_t ws_size,
                              hipStream_t stream)
{
    const float* embs = (const float*)d_in[0];
    const float* Wcx  = (const float*)d_in[1];
    const float* bcx  = (const float*)d_in[2];
    const float* Wox  = (const float*)d_in[3];
    const float* box  = (const float*)d_in[4];
    const float* Wl   = (const float*)d_in[5];
    const float* bl   = (const float*)d_in[6];
    const float* Wr   = (const float*)d_in[7];
    const float* br   = (const float*)d_in[8];

    char* p = (char*)d_ws;
    ushort* Wb2 = (ushort*)p;  p += (size_t)524288 * 2;
    ushort* WbL = (ushort*)p;  p += (size_t)163840 * 2;
    float*  bp2 = (float*)p;   p += 1024 * 4;
    float*  bpL = (float*)p;   p += 512 * 4;
    float*  c0  = (float*)p;   p += (size_t)65536 * 256 * 4;   // 64 MB
    ushort* h0  = (ushort*)p;  p += (size_t)65536 * 256 * 2;   // 32 MB
    char* X = p;
    ushort* embsB = (ushort*)X;                                 // 40 MB (dead after leaf)
    float*  cA = (float*)X;                                     // 32 MB
    ushort* hA = (ushort*)(X + (size_t)32768 * 256 * 4);        // 16 MB
    float*  cB = (float*)(X + (size_t)48 * 1024 * 1024);        // 16 MB
    ushort* hB = (ushort*)(X + (size_t)64 * 1024 * 1024);       // 8 MB

    conv_embs<<<20480, 256, 0, stream>>>(embs, embsB);
    pack_leaf_k<<<640, 256, 0, stream>>>(Wcx, Wox, bcx, box, WbL, bpL);
    pack_level_k<<<2048, 256, 0, stream>>>(Wl, Wr, bl, br, Wb2, bp2);

    // leaf: (65536,320) @ (320, 2*256) -> c0 fp32, h0 bf16.  NO=128 -> y=2
    mfma_gemm<2, 10, 0><<<dim3(256, 2), 512, 0, stream>>>(
        embsB, WbL, bpL, nullptr, c0, h0, nullptr, 65536);

    const ushort* hin = h0;
    const float*  cin = c0;
    float*  cping[2] = {cA, cB};
    ushort* hping[2] = {hA, hB};
    int flip = 0;
    for (int np = 512; np >= 1; np >>= 1) {
        int M = 64 * np;
        int gx = (M + 255) / 256;
        if (np == 1) {
            mfma_gemm<4, 16, 2><<<dim3(1, 4), 512, 0, stream>>>(
                hin, Wb2, bp2, cin, (float*)d_out, nullptr, (float*)d_out + 64 * 256, 64);
        } else {
            float* co = cping[flip]; ushort* ho = hping[flip];
            mfma_gemm<4, 16, 1><<<dim3(gx, 4), 512, 0, stream>>>(
                hin, Wb2, bp2, cin, co, ho, nullptr, M);
            cin = co; hin = ho; flip ^= 1;
        }
    }
}

// Round 6
// 299.373 us; speedup vs baseline: 1.3618x; 1.3618x over previous
//
#include <hip/hip_runtime.h>
#include <hip/hip_bf16.h>

// BinaryTreeLSTM  B=64, L=1024, IN_DIM=300, MEM=256 — bf16 MFMA v6
// "occupancy-first": small blocks, simple 2-buffer loop, rely on multi-block
// overlap (m114) instead of intra-block pipelining.
//
//  - block 128 rows x 128 G-cols, 256 threads = 4 waves (2 wm x 2 wn);
//    wave tile 64r x 64G = 4 m-frags x 4 f-frags -> acc 64 VGPR.
//  - LDS 32 KB: 2 bufs x (A 8KB + B 8KB). ~4 blocks/CU co-resident.
//  - K-loop: sync -> issue next-half global_load_lds(16B) -> ds_read frags
//    -> 16 MFMA. One barrier per K-32 half.
//  - v4-verified conflict-free swizzles (0 bank conflicts measured):
//      A: stored q = (slot - ((row>>1)&3))&3, read slot = (lq + ((lr>>1)&3))&3
//      B: pack   q = slot ^ ((o>>1)&3),       read slot = lq ^ ((lr>>1)&3)
//  - gates de-interleaved (col j = g*256+o) -> gate combine lane-local.
//  - c carried fp32, h carried bf16.

typedef __attribute__((ext_vector_type(8))) short bf16x8;
typedef __attribute__((ext_vector_type(4))) float f32x4;

__device__ __forceinline__ float fsig(float x)  { return 1.f / (1.f + __expf(-x)); }
__device__ __forceinline__ float ftanh(float x) { return 1.f - 2.f / (__expf(2.f * x) + 1.f); }
__device__ __forceinline__ ushort f2bf(float x) {
    __hip_bfloat16 b = __float2bfloat16(x);
    return *reinterpret_cast<ushort*>(&b);
}

__device__ __forceinline__ void gld_lds16(const void* g, void* l) {
    __builtin_amdgcn_global_load_lds((const __attribute__((address_space(1))) void*)g,
                                     (__attribute__((address_space(3))) void*)l, 16, 0, 0);
}

// ---------------- embs fp32 -> bf16 (pad K 300->320) ----------------
__global__ void conv_embs(const float* __restrict__ E, ushort* __restrict__ Eb)
{
    int tid = blockIdx.x * 256 + threadIdx.x;
    int row = tid / 80;
    int k = (tid - row * 80) * 4;
    float4 v = make_float4(0.f, 0.f, 0.f, 0.f);
    if (k < 300) v = *(const float4*)(E + (size_t)row * 300 + k);
    ushort4 o;
    o.x = f2bf(v.x); o.y = f2bf(v.y); o.z = f2bf(v.z); o.w = f2bf(v.w);
    *(ushort4*)(Eb + (size_t)row * 320 + k) = o;
}

// ---------------- weight pack kernels (v4-verified swizzle) ----------------
// chunk (t, g, o, slot) holds B[k = t*32 + q*8 + e][g*256+o], q = slot ^ ((o>>1)&3)
__global__ void pack_leaf_k(const float* __restrict__ Wcx, const float* __restrict__ Wox,
                            const float* __restrict__ bcx, const float* __restrict__ box,
                            ushort* __restrict__ Wb, float* __restrict__ bp)
{
    int idx = blockIdx.x * 256 + threadIdx.x;
    if (idx < 163840) {
        int e = idx & 7, slot = (idx >> 3) & 3, o = (idx >> 5) & 255;
        int g = (idx >> 13) & 1, t = idx >> 14;
        int q = slot ^ ((o >> 1) & 3);
        int k = t * 32 + q * 8 + e;
        float v = 0.f;
        if (k < 300) v = g ? Wox[o * 300 + k] : Wcx[o * 300 + k];
        Wb[idx] = f2bf(v);
    }
    if (idx < 512) {
        int g = idx >> 8, o = idx & 255;
        bp[idx] = g ? box[o] : bcx[o];
    }
}

__global__ void pack_level_k(const float* __restrict__ Wl, const float* __restrict__ Wr,
                             const float* __restrict__ bl, const float* __restrict__ br,
                             ushort* __restrict__ Wb, float* __restrict__ bp)
{
    int idx = blockIdx.x * 256 + threadIdx.x;
    if (idx < 524288) {
        int e = idx & 7, slot = (idx >> 3) & 3, o = (idx >> 5) & 255;
        int g = (idx >> 13) & 3, t = idx >> 15;
        int q = slot ^ ((o >> 1) & 3);
        int k = t * 32 + q * 8 + e;
        float v = (k < 256) ? Wl[(g * 256 + o) * 256 + k]
                            : Wr[(g * 256 + o) * 256 + (k - 256)];
        Wb[idx] = f2bf(v);
    }
    if (idx < 1024) bp[idx] = bl[idx] + br[idx];
}

// ---------------- fused MFMA GEMM, occupancy-first ----------------
// NG=2 leaf (o-width/block 64), NG=4 level (o-width 32).
// MODE 0 = leaf, 1 = level (h->bf16), 2 = last level (h->fp32)

template<int NG, int HALVES, int MODE>
__global__ __launch_bounds__(256, 4)
void mfma_gemm(const ushort* __restrict__ A,     // (M, HALVES*32) bf16 row-major
               const ushort* __restrict__ Wb,    // packed weights
               const float* __restrict__ bp,     // (NG*256)
               const float* __restrict__ Cprev,  // (M, 512) fp32, levels only
               float* __restrict__ c_out,        // (M, 256) fp32
               ushort* __restrict__ h_out,       // (M, 256) bf16 (MODE 0/1)
               float* __restrict__ hf_out,       // (M, 256) fp32 (MODE 2)
               int M)
{
    constexpr int K = HALVES * 32;
    constexpr int OW = 128 / NG;                  // o-cols per block
    // LDS: per buf 512 A-chunks + 512 B-chunks, 16 B each
    __shared__ __align__(16) ushort As[2][512 * 8];
    __shared__ __align__(16) ushort Bs[2][512 * 8];

    const int tid = threadIdx.x;
    const int wid = tid >> 6, ln = tid & 63;
    const int lq = ln >> 4, lr = ln & 15;
    const int wm = wid >> 1, wn = wid & 1;
    const int rowBlk = blockIdx.x * 128;
    const int o0 = blockIdx.y * OW;

    f32x4 acc[4][4];
#pragma unroll
    for (int m = 0; m < 4; ++m)
#pragma unroll
        for (int f = 0; f < 4; ++f) acc[m][f] = f32x4{0.f, 0.f, 0.f, 0.f};

    // ---- staging sources: thread stages A chunks {tid, tid+256}, B {tid, tid+256}
    //      A chunk c: row=c>>2, slot=c&3, stored q=(slot-((row>>1)&3))&3
    const int ar0 = tid >> 2,  as0 = tid & 3;
    const int ar1 = ar0 + 64;
    const int aq0 = (as0 - ((ar0 >> 1) & 3)) & 3;
    const int aq1 = (as0 - ((ar1 >> 1) & 3)) & 3;
    const ushort* aP0 = A + (size_t)min(rowBlk + ar0, M - 1) * K + aq0 * 8;
    const ushort* aP1 = A + (size_t)min(rowBlk + ar1, M - 1) * K + aq1 * 8;
    //      B chunk c: j=c>>2, slot=c&3; g=j/OW, o=o0+(j%OW); src=(h*NG+g)*1024+o*4+slot
    const int bj0 = tid >> 2,        bs0 = tid & 3;
    const int bj1 = (tid + 256) >> 2;
    const int bg0 = bj0 / OW, bo0 = o0 + (bj0 & (OW - 1));
    const int bg1 = bj1 / OW, bo1 = o0 + (bj1 & (OW - 1));
    const ushort* bP0 = Wb + ((size_t)bg0 * 1024 + bo0 * 4 + bs0) * 8;
    const ushort* bP1 = Wb + ((size_t)bg1 * 1024 + bo1 * 4 + bs0) * 8;
    constexpr size_t BSTR = (size_t)NG * 1024 * 8;   // Wb ushorts per half

    // ---- read swizzles (v4-verified)
    const int aSw = (lq + ((lr >> 1) & 3)) & 3;
    const int bSw = lq ^ ((lr >> 1) & 3);
    int aOff[4];
#pragma unroll
    for (int m = 0; m < 4; ++m)
        aOff[m] = ((wm * 64 + m * 16 + lr) * 4 + aSw) * 8;
    int bOff[4];
#pragma unroll
    for (int f = 0; f < 4; ++f)
        bOff[f] = ((f * 32 + wn * 16 + lr) * 4 + bSw) * 8;

    // ---- prologue: stage half 0 into buf 0
    gld_lds16(aP0, &As[0][tid * 8]);
    gld_lds16(aP1, &As[0][(tid + 256) * 8]);
    gld_lds16(bP0, &Bs[0][tid * 8]);
    gld_lds16(bP1, &Bs[0][(tid + 256) * 8]);

#pragma unroll
    for (int h = 0; h < HALVES; ++h) {
        __syncthreads();               // drains vmcnt -> buf[cur] staged
        const int cur = h & 1;
        if (h + 1 < HALVES) {          // issue next-half staging into buf^1
            gld_lds16(aP0 + (size_t)(h + 1) * 32, &As[cur ^ 1][tid * 8]);
            gld_lds16(aP1 + (size_t)(h + 1) * 32, &As[cur ^ 1][(tid + 256) * 8]);
            gld_lds16(bP0 + (size_t)(h + 1) * BSTR, &Bs[cur ^ 1][tid * 8]);
            gld_lds16(bP1 + (size_t)(h + 1) * BSTR, &Bs[cur ^ 1][(tid + 256) * 8]);
        }
        bf16x8 a[4];
#pragma unroll
        for (int m = 0; m < 4; ++m)
            a[m] = *(const bf16x8*)&As[cur][aOff[m]];
#pragma unroll
        for (int f = 0; f < 4; ++f) {
            bf16x8 b = *(const bf16x8*)&Bs[cur][bOff[f]];
#pragma unroll
            for (int m = 0; m < 4; ++m)
                acc[m][f] = __builtin_amdgcn_mfma_f32_16x16x32_bf16(a[m], b, acc[m][f], 0, 0, 0);
        }
    }

    // ---- epilogue: D col = lr (within 16), row = 4*lq + j
#pragma unroll
    for (int m = 0; m < 4; ++m) {
        const int row0 = rowBlk + wm * 64 + m * 16 + lq * 4;
        if constexpr (MODE == 0) {
            // leaf: f = (gate<<1) | o-half;  col = o0 + (f&1)*32 + wn*16 + lr
#pragma unroll
            for (int ob = 0; ob < 2; ++ob) {
                const int col = o0 + ob * 32 + wn * 16 + lr;
                const float bc = bp[col], bo = bp[256 + col];
#pragma unroll
                for (int j = 0; j < 4; ++j) {
                    int row = row0 + j;
                    if (row < M) {
                        float cv = acc[m][ob][j] + bc;
                        float ov = acc[m][2 + ob][j] + bo;
                        c_out[(size_t)row * 256 + col] = cv;
                        h_out[(size_t)row * 256 + col] = f2bf(fsig(ov) * ftanh(cv));
                    }
                }
            }
        } else {
            // level: f = gate; col = o0 + wn*16 + lr
            const int col = o0 + wn * 16 + lr;
            const float bi  = bp[col],       blf = bp[256 + col];
            const float brf = bp[512 + col], bu  = bp[768 + col];
#pragma unroll
            for (int j = 0; j < 4; ++j) {
                int row = row0 + j;
                if (row < M) {
                    float gi = fsig(acc[m][0][j] + bi);
                    float lf = fsig(acc[m][1][j] + blf);
                    float rf = fsig(acc[m][2][j] + brf);
                    float gu = ftanh(acc[m][3][j] + bu);
                    float lc = Cprev[(size_t)row * 512 + col];
                    float rc = Cprev[(size_t)row * 512 + 256 + col];
                    float cv = gi * gu + lf * lc + rf * rc;
                    float hv = ftanh(cv);
                    c_out[(size_t)row * 256 + col] = cv;
                    if constexpr (MODE == 2) hf_out[(size_t)row * 256 + col] = hv;
                    else                     h_out[(size_t)row * 256 + col] = f2bf(hv);
                }
            }
        }
    }
}

// ---------------- host ----------------

extern "C" void kernel_launch(void* const* d_in, const int* in_sizes, int n_in,
                              void* d_out, int out_size, void* d_ws, size_t ws_size,
                              hipStream_t stream)
{
    const float* embs = (const float*)d_in[0];
    const float* Wcx  = (const float*)d_in[1];
    const float* bcx  = (const float*)d_in[2];
    const float* Wox  = (const float*)d_in[3];
    const float* box  = (const float*)d_in[4];
    const float* Wl   = (const float*)d_in[5];
    const float* bl   = (const float*)d_in[6];
    const float* Wr   = (const float*)d_in[7];
    const float* br   = (const float*)d_in[8];

    char* p = (char*)d_ws;
    ushort* Wb2 = (ushort*)p;  p += (size_t)524288 * 2;
    ushort* WbL = (ushort*)p;  p += (size_t)163840 * 2;
    float*  bp2 = (float*)p;   p += 1024 * 4;
    float*  bpL = (float*)p;   p += 512 * 4;
    float*  c0  = (float*)p;   p += (size_t)65536 * 256 * 4;   // 64 MB
    ushort* h0  = (ushort*)p;  p += (size_t)65536 * 256 * 2;   // 32 MB
    char* X = p;
    ushort* embsB = (ushort*)X;                                 // 40 MB (dead after leaf)
    float*  cA = (float*)X;                                     // 32 MB
    ushort* hA = (ushort*)(X + (size_t)32768 * 256 * 4);        // 16 MB
    float*  cB = (float*)(X + (size_t)48 * 1024 * 1024);        // 16 MB
    ushort* hB = (ushort*)(X + (size_t)64 * 1024 * 1024);       // 8 MB

    conv_embs<<<20480, 256, 0, stream>>>(embs, embsB);
    pack_leaf_k<<<640, 256, 0, stream>>>(Wcx, Wox, bcx, box, WbL, bpL);
    pack_level_k<<<2048, 256, 0, stream>>>(Wl, Wr, bl, br, Wb2, bp2);

    // leaf: (65536,320) @ (320, 2*256) -> c0 fp32, h0 bf16.  y=4 (OW=64)
    mfma_gemm<2, 10, 0><<<dim3(512, 4), 256, 0, stream>>>(
        embsB, WbL, bpL, nullptr, c0, h0, nullptr, 65536);

    const ushort* hin = h0;
    const float*  cin = c0;
    float*  cping[2] = {cA, cB};
    ushort* hping[2] = {hA, hB};
    int flip = 0;
    for (int np = 512; np >= 1; np >>= 1) {
        int M = 64 * np;
        int gx = (M + 127) / 128;
        if (np == 1) {
            mfma_gemm<4, 16, 2><<<dim3(gx, 8), 256, 0, stream>>>(
                hin, Wb2, bp2, cin, (float*)d_out, nullptr, (float*)d_out + 64 * 256, M);
        } else {
            float* co = cping[flip]; ushort* ho = hping[flip];
            mfma_gemm<4, 16, 1><<<dim3(gx, 8), 256, 0, stream>>>(
                hin, Wb2, bp2, cin, co, ho, nullptr, M);
            cin = co; hin = ho; flip ^= 1;
        }
    }
}